// Round 5
// baseline (205.617 us; speedup 1.0000x reference)
//
#include <hip/hip_runtime.h>
#include <stdint.h>

// HingeLoss: B=4M rows, 7 classes.
// elem = mask ? |logit - target| : relu(logit - target); out = sum(elem)
//
// R5: probe hypothesis "VGPR-return load path caps at ~2.6 TB/s".
// Double-buffered global_load_lds (direct-to-LDS DMA, bypasses L1/VGPR
// return) with counted vmcnt + raw s_barrier (NOT __syncthreads, which
// drains vmcnt(0) and would kill the prefetch).

#define NCLS 7
#define T_ROWS 256
#define LOG_B  (T_ROWS * NCLS * 4)   // 7168
#define LAB_B  (T_ROWS * 4)          // 1024
#define REP_B  (T_ROWS * 3 * 4)      // 3072
#define TILE_B (LOG_B + LAB_B + REP_B) // 11264
#define NBLK 1792                    // 7 blocks/CU (22.5 KB LDS each)

typedef const __attribute__((address_space(1))) void g_void;
typedef __attribute__((address_space(3))) void l_void;

__device__ __forceinline__ void stage16(const char* g, char* l) {
    // moves 64 lanes x 16 B = 1024 B; LDS dest = uniform base + lane*16,
    // global src must include + lane*16 (per-lane address).
    __builtin_amdgcn_global_load_lds((g_void*)g, (l_void*)l, 16, 0, 0);
}

__global__ __launch_bounds__(256) void hinge_stage_kernel(
    const char* __restrict__ glog,    // logit  [B*28 B]
    const char* __restrict__ glab,    // label  [B*4 B]
    const char* __restrict__ grep,    // repr   [B*12 B]
    float* __restrict__ partials,     // [gridDim.x]
    int ntiles)
{
    __shared__ char lds[2 * TILE_B];

    const int tid  = threadIdx.x;
    const int lane = tid & 63;
    const int wid  = tid >> 6;
    const int lofs = lane * 16;

    float acc = 0.0f;
    int cur = 0;

    const int t0 = blockIdx.x;

    // prologue: stage first tile into buffer 0 (wave 0 only)
    if (t0 < ntiles && wid == 0) {
        const char* gl = glog + (size_t)t0 * LOG_B + lofs;
        const char* gb = glab + (size_t)t0 * LAB_B + lofs;
        const char* gr = grep + (size_t)t0 * REP_B + lofs;
        char* L = lds;
        #pragma unroll
        for (int c = 0; c < 7; ++c) stage16(gl + c * 1024, L + c * 1024);
        stage16(gb, L + LOG_B);
        #pragma unroll
        for (int c = 0; c < 3; ++c) stage16(gr + c * 1024, L + LOG_B + LAB_B + c * 1024);
    }

    for (int t = t0; t < ntiles; t += NBLK) {
        const int tn = t + NBLK;
        if (wid == 0) {
            if (tn < ntiles) {
                // issue next-tile stage into the other buffer (11 more in flight)
                const char* gl = glog + (size_t)tn * LOG_B + lofs;
                const char* gb = glab + (size_t)tn * LAB_B + lofs;
                const char* gr = grep + (size_t)tn * REP_B + lofs;
                char* L = lds + (cur ^ 1) * TILE_B;
                #pragma unroll
                for (int c = 0; c < 7; ++c) stage16(gl + c * 1024, L + c * 1024);
                stage16(gb, L + LOG_B);
                #pragma unroll
                for (int c = 0; c < 3; ++c) stage16(gr + c * 1024, L + LOG_B + LAB_B + c * 1024);
                // wait for tile t's 11 loads (oldest); leave tile tn's 11 in flight
                asm volatile("s_waitcnt vmcnt(11)" ::: "memory");
            } else {
                asm volatile("s_waitcnt vmcnt(0)" ::: "memory");
            }
        }
        __builtin_amdgcn_s_barrier();   // tile t visible to all waves

        // ---- compute: 1 row per thread from LDS ----
        {
            const float* sl = (const float*)(lds + cur * TILE_B);
            const int*   sb = (const int*)(lds + cur * TILE_B + LOG_B);
            const int*   sr = (const int*)(lds + cur * TILE_B + LOG_B + LAB_B);
            const int r = tid;
            float tgt = (sb[r] == 1) ? 1.0f : 0.0f;
            unsigned m = (1u << sr[3 * r]) | (1u << sr[3 * r + 1]) | (1u << sr[3 * r + 2]);
            #pragma unroll
            for (int j = 0; j < NCLS; ++j) {
                float d = sl[r * NCLS + j] - tgt;   // bank = (7r+j)%32, gcd(7,32)=1 -> 2-way (free)
                acc += ((m >> j) & 1u) ? fabsf(d) : fmaxf(d, 0.0f);
            }
        }

        __builtin_amdgcn_s_barrier();   // all waves done reading buf cur
        cur ^= 1;
    }

    // ---- wave reduce + one contention-free store per block ----
    #pragma unroll
    for (int off = 32; off > 0; off >>= 1)
        acc += __shfl_down(acc, off, 64);

    __shared__ float wave_sums[4];
    if ((tid & 63) == 0) wave_sums[tid >> 6] = acc;
    __syncthreads();
    if (tid == 0)
        partials[blockIdx.x] = wave_sums[0] + wave_sums[1] + wave_sums[2] + wave_sums[3];
}

__global__ __launch_bounds__(256) void reduce_partials_kernel(
    const float* __restrict__ partials, int n,
    const float* __restrict__ logit, const int* __restrict__ label,
    const int* __restrict__ repr, int tail_start, int B,
    float* __restrict__ out)
{
    float a = 0.0f;
    for (int i = threadIdx.x; i < n; i += 256)
        a += partials[i];

    // tail rows not covered by full tiles (B % 256; zero for B=4M)
    for (int i = tail_start + threadIdx.x; i < B; i += 256) {
        float tgt = (label[i] == 1) ? 1.0f : 0.0f;
        unsigned m = (1u << repr[3 * i]) | (1u << repr[3 * i + 1]) | (1u << repr[3 * i + 2]);
        #pragma unroll
        for (int j = 0; j < NCLS; ++j) {
            float d = logit[i * NCLS + j] - tgt;
            a += ((m >> j) & 1u) ? fabsf(d) : fmaxf(d, 0.0f);
        }
    }

    #pragma unroll
    for (int off = 32; off > 0; off >>= 1)
        a += __shfl_down(a, off, 64);

    __shared__ float wave_sums[4];
    if ((threadIdx.x & 63) == 0) wave_sums[threadIdx.x >> 6] = a;
    __syncthreads();
    if (threadIdx.x == 0)
        out[0] = wave_sums[0] + wave_sums[1] + wave_sums[2] + wave_sums[3];
}

extern "C" void kernel_launch(void* const* d_in, const int* in_sizes, int n_in,
                              void* d_out, int out_size, void* d_ws, size_t ws_size,
                              hipStream_t stream) {
    const char* glog = (const char*)d_in[0];
    const char* glab = (const char*)d_in[1];
    const char* grep = (const char*)d_in[2];
    float*      out  = (float*)d_out;
    float*      partials = (float*)d_ws;

    int B = in_sizes[1];              // label is [B]
    int ntiles = B / T_ROWS;          // 15625 for B=4M
    int tail_start = ntiles * T_ROWS; // == B (no tail) for B=4M

    hinge_stage_kernel<<<NBLK, 256, 0, stream>>>(glog, glab, grep, partials, ntiles);
    reduce_partials_kernel<<<1, 256, 0, stream>>>(
        partials, NBLK, (const float*)d_in[0], (const int*)d_in[1],
        (const int*)d_in[2], tail_start, B, out);
}